// Round 4
// baseline (58.062 us; speedup 1.0000x reference)
//
#include <hip/hip_runtime.h>
#include <hip/hip_bf16.h>

#define BB 2
#define NN 4096
#define LL 256
#define DD 2048
#define CC 6
#define EPSF 1e-6f

__device__ __forceinline__ float dot4(float4 a, float4 b) {
    return a.x * b.x + a.y * b.y + a.z * b.z + a.w * b.w;
}

__device__ __forceinline__ void keep4(float4 v) {
    asm volatile("" :: "v"(v.x), "v"(v.y), "v"(v.z), "v"(v.w));
}

// ---------------------------------------------------------------------------
// K1: cluster softmax -> cw (B,L,C).  bids 0..511 compute one (b,l) row;
//     bids 512..1023 prefetch first half of x into L3 (read + keep-alive).
__global__ __launch_bounds__(256) void k_cluster(const float* __restrict__ te,
                                                 const float* __restrict__ Wc,
                                                 float* __restrict__ cw,
                                                 const float4* __restrict__ x4) {
    const int tid = threadIdx.x;
    if (blockIdx.x >= 512) {
        size_t i = (size_t)(blockIdx.x - 512) * 256 + tid;
#pragma unroll
        for (int k = 0; k < 16; ++k, i += 512 * 256) keep4(x4[i]);
        return;
    }
    const int row = blockIdx.x;              // b*LL + l
    const float4* t4 = (const float4*)(te + (size_t)row * DD);
    float p[CC];
#pragma unroll
    for (int c = 0; c < CC; ++c) p[c] = 0.f;
#pragma unroll
    for (int it = 0; it < 2; ++it) {
        const int i = it * 256 + tid;
        const float4 xv = t4[i];
#pragma unroll
        for (int c = 0; c < CC; ++c)
            p[c] += dot4(xv, ((const float4*)(Wc + (size_t)c * DD))[i]);
    }
#pragma unroll
    for (int c = 0; c < CC; ++c)
        for (int off = 32; off; off >>= 1) p[c] += __shfl_down(p[c], off);
    __shared__ float sred[4][CC];
    const int lane = tid & 63, wid = tid >> 6;
    if (lane == 0) {
#pragma unroll
        for (int c = 0; c < CC; ++c) sred[wid][c] = p[c];
    }
    __syncthreads();
    if (tid == 0) {
        float lg[CC], m = -1e30f;
#pragma unroll
        for (int c = 0; c < CC; ++c) {
            lg[c] = sred[0][c] + sred[1][c] + sred[2][c] + sred[3][c];
            m = fmaxf(m, lg[c]);
        }
        float s = 0.f;
#pragma unroll
        for (int c = 0; c < CC; ++c) { lg[c] = __expf(lg[c] - m); s += lg[c]; }
        const float inv = 1.f / s;
#pragma unroll
        for (int c = 0; c < CC; ++c) cw[row * CC + c] = lg[c] * inv;
    }
}

// ---------------------------------------------------------------------------
// K2: concept_reps -> cr (B,C,D).  bids 0..63 compute; bids 64..575 prefetch
//     second half of x into L3.
__global__ __launch_bounds__(256) void k_creps(const float* __restrict__ te,
                                               const float* __restrict__ cw,
                                               float* __restrict__ cr,
                                               const float4* __restrict__ x4) {
    const int tid = threadIdx.x;
    if (blockIdx.x >= 64) {
        const size_t HALF4 = (size_t)BB * NN * DD / 8;   // 2,097,152
        size_t i = HALF4 + (size_t)(blockIdx.x - 64) * 256 + tid;
#pragma unroll
        for (int k = 0; k < 16; ++k, i += 512 * 256) keep4(x4[i]);
        return;
    }
    const int b = blockIdx.x >> 5;
    const int d0 = (blockIdx.x & 31) * 64;
    const int lane = tid & 63, wid = tid >> 6;
    __shared__ float scw[LL * CC];                       // 6 KB
    __shared__ float sacc[4][64][CC];                    // 6 KB
    for (int i = tid; i < LL * CC; i += 256) scw[i] = cw[b * LL * CC + i];
    __syncthreads();
    float acc[CC];
#pragma unroll
    for (int c = 0; c < CC; ++c) acc[c] = 0.f;
    const float* tb = te + ((size_t)b * LL + wid * 64) * DD + d0 + lane;
    for (int l = 0; l < 64; ++l) {
        const float xv = tb[(size_t)l * DD];
        const int gl = wid * 64 + l;
#pragma unroll
        for (int c = 0; c < CC; ++c) acc[c] = fmaf(scw[gl * CC + c], xv, acc[c]);
    }
#pragma unroll
    for (int c = 0; c < CC; ++c) sacc[wid][lane][c] = acc[c];
    __syncthreads();
    if (tid < 64) {
#pragma unroll
        for (int c = 0; c < CC; ++c) {
            const float s = sacc[0][tid][c] + sacc[1][tid][c] +
                            sacc[2][tid][c] + sacc[3][tid][c];
            cr[((size_t)b * CC + c) * DD + d0 + tid] = s;
        }
    }
}

// ---------------------------------------------------------------------------
// K3: v = cr.Wv^T + blend-softmax + unbiased-var gate -> fused (B,D).
//     bids 0..255 compute (2 e per wave); bids 256..511 prefetch Wo into L3.
__global__ __launch_bounds__(256) void k_vfuse(const float* __restrict__ cr,
                                               const float* __restrict__ Wv,
                                               const float* __restrict__ blendw,
                                               const float* __restrict__ sgate,
                                               const int* __restrict__ issur,
                                               float* __restrict__ fused,
                                               const float4* __restrict__ Wo4) {
    const int tid = threadIdx.x;
    if (blockIdx.x >= 256) {
        size_t i = (size_t)(blockIdx.x - 256) * 256 + tid;
#pragma unroll
        for (int k = 0; k < 16; ++k, i += 256 * 256) keep4(Wo4[i]);
        return;
    }
    const int lane = tid & 63, wid = tid >> 6;
    const int e0 = blockIdx.x * 8 + wid * 2;             // this wave's 2 e's
    float acc[BB][2][CC];
#pragma unroll
    for (int b = 0; b < BB; ++b)
#pragma unroll
        for (int j = 0; j < 2; ++j)
#pragma unroll
            for (int c = 0; c < CC; ++c) acc[b][j][c] = 0.f;
#pragma unroll
    for (int it = 0; it < 8; ++it) {
        const int d = it * 256 + lane * 4;
        const float4 w0 = *(const float4*)(Wv + (size_t)e0 * DD + d);
        const float4 w1 = *(const float4*)(Wv + (size_t)(e0 + 1) * DD + d);
#pragma unroll
        for (int b = 0; b < BB; ++b)
#pragma unroll
            for (int c = 0; c < CC; ++c) {
                const float4 cv = *(const float4*)(cr + ((size_t)b * CC + c) * DD + d);
                acc[b][0][c] += dot4(cv, w0);
                acc[b][1][c] += dot4(cv, w1);
            }
    }
#pragma unroll
    for (int b = 0; b < BB; ++b)
#pragma unroll
        for (int j = 0; j < 2; ++j)
#pragma unroll
            for (int c = 0; c < CC; ++c)
                for (int off = 32; off; off >>= 1)
                    acc[b][j][c] += __shfl_down(acc[b][j][c], off);
    if (lane == 0) {
        float bw[CC], m = -1e30f;
#pragma unroll
        for (int c = 0; c < CC; ++c) { bw[c] = blendw[c]; m = fmaxf(m, bw[c]); }
        float s = 0.f;
#pragma unroll
        for (int c = 0; c < CC; ++c) { bw[c] = __expf(bw[c] - m); s += bw[c]; }
        const float inv = 1.f / s;
#pragma unroll
        for (int c = 0; c < CC; ++c) bw[c] *= inv;
        const float gate = 1.f / (1.f + __expf(-sgate[0]));
        const int sur = issur[0];
#pragma unroll
        for (int b = 0; b < BB; ++b)
#pragma unroll
            for (int j = 0; j < 2; ++j) {
                float f = 0.f, mean = 0.f;
#pragma unroll
                for (int c = 0; c < CC; ++c) {
                    f = fmaf(bw[c], acc[b][j][c], f);
                    mean += acc[b][j][c];
                }
                mean *= (1.f / CC);
                float var = 0.f;
#pragma unroll
                for (int c = 0; c < CC; ++c) {
                    const float dv = acc[b][j][c] - mean;
                    var = fmaf(dv, dv, var);
                }
                var *= (1.f / (CC - 1));                 // ddof=1
                if (sur) f = fmaf(gate * var, 0.3f, f);
                fused[b * DD + e0 + j] = f;
            }
    }
}

// ---------------------------------------------------------------------------
// K4: RMS scales (per-block recompute from L2-resident fused) + out-proj GEMV.
__global__ __launch_bounds__(256) void k_rmsout(const float* __restrict__ fused,
                                                const float* __restrict__ nw,
                                                const float* __restrict__ Wo,
                                                float* __restrict__ o) {
    const int tid = threadIdx.x;
    const int lane = tid & 63, wid = tid >> 6;
    float ss[BB];
#pragma unroll
    for (int b = 0; b < BB; ++b) ss[b] = 0.f;
#pragma unroll
    for (int k = 0; k < DD / 256; ++k) {
        const int d = k * 256 + tid;
#pragma unroll
        for (int b = 0; b < BB; ++b) {
            const float v = fused[b * DD + d];
            ss[b] = fmaf(v, v, ss[b]);
        }
    }
#pragma unroll
    for (int b = 0; b < BB; ++b)
        for (int off = 32; off; off >>= 1) ss[b] += __shfl_down(ss[b], off);
    __shared__ float sred[4][BB];
    __shared__ float sscale[BB];
    if (lane == 0) {
#pragma unroll
        for (int b = 0; b < BB; ++b) sred[wid][b] = ss[b];
    }
    __syncthreads();
    if (tid == 0) {
#pragma unroll
        for (int b = 0; b < BB; ++b) {
            const float tot = sred[0][b] + sred[1][b] + sred[2][b] + sred[3][b];
            sscale[b] = rsqrtf(tot * (1.f / DD) + EPSF);
        }
    }
    __syncthreads();
    const int e = blockIdx.x * 4 + wid;
    float acc[BB];
#pragma unroll
    for (int b = 0; b < BB; ++b) acc[b] = 0.f;
#pragma unroll
    for (int it = 0; it < DD / 256; ++it) {
        const int d = it * 256 + lane * 4;
        const float4 wv = *(const float4*)(Wo + (size_t)e * DD + d);
        const float4 nv = *(const float4*)(nw + d);
        float4 t;
        t.x = wv.x * nv.x; t.y = wv.y * nv.y; t.z = wv.z * nv.z; t.w = wv.w * nv.w;
#pragma unroll
        for (int b = 0; b < BB; ++b) {
            const float4 fv = *(const float4*)(fused + (size_t)b * DD + d);
            acc[b] += dot4(fv, t);
        }
    }
#pragma unroll
    for (int b = 0; b < BB; ++b) {
        for (int off = 32; off; off >>= 1) acc[b] += __shfl_down(acc[b], off);
        if (lane == 0) o[b * DD + e] = acc[b] * sscale[b];
    }
}

// ---------------------------------------------------------------------------
// K5: out[b,n,e] = x[b,n,e] + o[b,e]   (x should be L3-resident by now)
__global__ __launch_bounds__(256) void k_add(const float* __restrict__ x,
                                             const float* __restrict__ o,
                                             float* __restrict__ out) {
    const float4* x4 = (const float4*)x;
    const float4* o4 = (const float4*)o;
    float4* out4 = (float4*)out;
    size_t f = (size_t)blockIdx.x * 256 + threadIdx.x;
#pragma unroll
    for (int k = 0; k < 8; ++k, f += (size_t)2048 * 256) {
        const int e4 = (int)(f & (DD / 4 - 1));
        const int b = (int)(f >> 21);                 // NN*DD/4 = 2^21
        const float4 xv = x4[f];
        const float4 ov = o4[b * (DD / 4) + e4];
        float4 r;
        r.x = xv.x + ov.x; r.y = xv.y + ov.y;
        r.z = xv.z + ov.z; r.w = xv.w + ov.w;
        out4[f] = r;
    }
}

extern "C" void kernel_launch(void* const* d_in, const int* in_sizes, int n_in,
                              void* d_out, int out_size, void* d_ws, size_t ws_size,
                              hipStream_t stream) {
    const float* x  = (const float*)d_in[0];
    const float* te = (const float*)d_in[1];
    const float* Wc = (const float*)d_in[2];
    // d_in[3] = Wq, d_in[4] = Wk : unused (softmax over a single key == 1)
    const float* Wv = (const float*)d_in[5];
    const float* Wo = (const float*)d_in[6];
    const float* bw = (const float*)d_in[7];
    const float* sg = (const float*)d_in[8];
    const float* nw = (const float*)d_in[9];
    const int* isur = (const int*)d_in[10];
    float* out = (float*)d_out;

    float* ws     = (float*)d_ws;
    float* cw     = ws;                       // B*L*C  = 3072 (pad to 4096)
    float* cr     = ws + 4096;                // B*C*D  = 24576
    float* fusedv = ws + 4096 + 24576;        // B*D    = 4096
    float* o      = fusedv + 4096;            // B*D    = 4096

    hipLaunchKernelGGL(k_cluster, dim3(1024), dim3(256), 0, stream,
                       te, Wc, cw, (const float4*)x);
    hipLaunchKernelGGL(k_creps,   dim3(576),  dim3(256), 0, stream,
                       te, cw, cr, (const float4*)x);
    hipLaunchKernelGGL(k_vfuse,   dim3(512),  dim3(256), 0, stream,
                       cr, Wv, bw, sg, isur, fusedv, (const float4*)Wo);
    hipLaunchKernelGGL(k_rmsout,  dim3(DD / 4), dim3(256), 0, stream,
                       fusedv, nw, Wo, o);
    hipLaunchKernelGGL(k_add,     dim3(2048), dim3(256), 0, stream, x, o, out);
}